// Round 1
// baseline (476.532 us; speedup 1.0000x reference)
//
#include <hip/hip_runtime.h>
#include <hip/hip_bf16.h>

typedef __bf16 bf16x8 __attribute__((ext_vector_type(8)));
typedef float f32x4 __attribute__((ext_vector_type(4)));

// LDS byte offsets
#define LDS_HO 0        // 64 rows x 512B (h_other bf16 64x256); reused for h_new tile (64x128 bf16, stride 256)
#define LDS_X  32768    // 64 rows x 256B (x = [enc_in | enc_hid] bf16 64x128)
#define LDS_H  49152    // 64 rows x 256B (h bf16 64x128)

// workspace element offsets (ushort/bf16)
#define WS_WIH 0
#define WS_WHH 49152
#define WS_HENC 98304
#define WS_DEC 114688
#define WS_TOTAL 116736

__device__ __forceinline__ unsigned short f2bf(float f) {
    unsigned u = __float_as_uint(f);
    unsigned r = (u + 0x7FFFu + ((u >> 16) & 1u)) >> 16;   // RNE
    return (unsigned short)r;
}

__device__ __forceinline__ float sigmf(float x) { return 1.0f / (1.0f + __expf(-x)); }
__device__ __forceinline__ float tanh_fast(float x) {
    float t = __expf(-2.0f * fabsf(x));
    float r = (1.0f - t) / (1.0f + t);
    return copysignf(r, x);
}

__global__ void convert_weights_kernel(const float* __restrict__ wih,
                                       const float* __restrict__ whh,
                                       const float* __restrict__ henc,
                                       const float* __restrict__ dec,
                                       unsigned short* __restrict__ ws) {
    int i = blockIdx.x * 256 + threadIdx.x;
    if (i >= WS_TOTAL) return;
    float v;
    if (i < WS_WHH)        v = wih[i];
    else if (i < WS_HENC)  v = whh[i - WS_WHH];
    else if (i < WS_DEC)   v = henc[i - WS_HENC];
    else { int d = i - WS_DEC; v = (d < 640) ? dec[d] : 0.0f; }   // dec padded to 16x128
    ws[i] = f2bf(v);
}

__launch_bounds__(256, 2)
__global__ void fused_rnn_kernel(const float* __restrict__ pos,
                                 const float* __restrict__ h_other,
                                 const float* __restrict__ h,
                                 const float* __restrict__ enc_W,
                                 const float* __restrict__ enc_b,
                                 const float* __restrict__ henc_b,
                                 const float* __restrict__ b_ih,
                                 const float* __restrict__ b_hh,
                                 const float* __restrict__ dec_b,
                                 const unsigned short* __restrict__ ws,
                                 float* __restrict__ out,
                                 float* __restrict__ hnew,
                                 int N) {
    __shared__ char sm[65536];
    const int tid = threadIdx.x;
    const int w   = tid >> 6;      // wave 0..3
    const int l   = tid & 63;
    const int lg  = l >> 4;        // lane group 0..3
    const int ln  = l & 15;
    const int row0 = blockIdx.x * 64;

    // ---------------- Phase 0: stage tiles ----------------
    // h_other -> LDS_HO (bf16, 64x256, stride 512B, xor-swizzled)
    #pragma unroll
    for (int j = 0; j < 16; ++j) {
        int e0  = (tid + 256 * j) * 4;
        int row = e0 >> 8;
        int col = e0 & 255;
        int grow = row0 + row; if (grow > N - 1) grow = N - 1;
        float4 v = *reinterpret_cast<const float4*>(h_other + (size_t)grow * 256 + col);
        uint2 p;
        p.x = (unsigned)f2bf(v.x) | ((unsigned)f2bf(v.y) << 16);
        p.y = (unsigned)f2bf(v.z) | ((unsigned)f2bf(v.w) << 16);
        int boff = LDS_HO + row * 512 + ((col * 2) ^ ((row & 7) << 4));
        *reinterpret_cast<uint2*>(sm + boff) = p;
    }
    // h -> LDS_H (bf16, 64x128, stride 256B)
    #pragma unroll
    for (int j = 0; j < 8; ++j) {
        int e0  = (tid + 256 * j) * 4;
        int row = e0 >> 7;
        int col = e0 & 127;
        int grow = row0 + row; if (grow > N - 1) grow = N - 1;
        float4 v = *reinterpret_cast<const float4*>(h + (size_t)grow * 128 + col);
        uint2 p;
        p.x = (unsigned)f2bf(v.x) | ((unsigned)f2bf(v.y) << 16);
        p.y = (unsigned)f2bf(v.z) | ((unsigned)f2bf(v.w) << 16);
        int boff = LDS_H + row * 256 + ((col * 2) ^ ((row & 7) << 4));
        *reinterpret_cast<uint2*>(sm + boff) = p;
    }
    // E1 = relu(pos @ enc_W.T + enc_b) -> LDS_X cols 0..63
    {
        int row = tid >> 2;
        int c0  = (tid & 3) * 16;
        int grow = row0 + row; if (grow > N - 1) grow = N - 1;
        float p0 = pos[(size_t)grow * 2 + 0];
        float p1 = pos[(size_t)grow * 2 + 1];
        #pragma unroll
        for (int q = 0; q < 8; ++q) {
            int c = c0 + q * 2;
            float v0 = fmaxf(p0 * enc_W[c * 2]     + p1 * enc_W[c * 2 + 1]  + enc_b[c], 0.f);
            float v1 = fmaxf(p0 * enc_W[c * 2 + 2] + p1 * enc_W[c * 2 + 3]  + enc_b[c + 1], 0.f);
            unsigned pk = (unsigned)f2bf(v0) | ((unsigned)f2bf(v1) << 16);
            int boff = LDS_X + row * 256 + ((c * 2) ^ ((row & 7) << 4));
            *reinterpret_cast<unsigned*>(sm + boff) = pk;
        }
    }
    __syncthreads();

    // ---------------- Phase 1: E2 = relu(h_other @ henc_W.T + henc_b) ----------------
    // wave w owns E2 cols [16w, 16w+16)
    {
        f32x4 acc[4];
        #pragma unroll
        for (int mt = 0; mt < 4; ++mt) acc[mt] = (f32x4){0.f, 0.f, 0.f, 0.f};
        #pragma unroll
        for (int ks = 0; ks < 8; ++ks) {
            bf16x8 af[4];
            #pragma unroll
            for (int mt = 0; mt < 4; ++mt) {
                int row = mt * 16 + ln;
                int boff = LDS_HO + row * 512 + ((ks * 64 + lg * 16) ^ ((row & 7) << 4));
                af[mt] = *reinterpret_cast<const bf16x8*>(sm + boff);
            }
            const unsigned short* bp = ws + WS_HENC + (size_t)(16 * w + ln) * 256 + ks * 32 + lg * 8;
            bf16x8 bf = *reinterpret_cast<const bf16x8*>(bp);
            #pragma unroll
            for (int mt = 0; mt < 4; ++mt)
                acc[mt] = __builtin_amdgcn_mfma_f32_16x16x32_bf16(af[mt], bf, acc[mt], 0, 0, 0);
        }
        int col = 16 * w + ln;
        float bias = henc_b[col];
        #pragma unroll
        for (int mt = 0; mt < 4; ++mt) {
            #pragma unroll
            for (int i = 0; i < 4; ++i) {
                int row = mt * 16 + lg * 4 + i;
                float v = fmaxf(acc[mt][i] + bias, 0.f);
                int boff = LDS_X + row * 256 + (((64 + col) * 2) ^ ((row & 7) << 4));
                *reinterpret_cast<unsigned short*>(sm + boff) = f2bf(v);
            }
        }
    }
    __syncthreads();

    // ---------------- Phase 2: gates ----------------
    // wave w owns gate columns [32w, 32w+32)
    // jobs 0,1: r (o=32w,32w+16, K=256 over [x|h], W=[W_ih|W_hh])
    // jobs 2,3: z (o=128+32w,...) ; jobs 4,5: xn (W_ih rows 256+, K=x) ; jobs 6,7: hn (W_hh rows 256+, K=h)
    {
        f32x4 acc[4][8];
        #pragma unroll
        for (int a = 0; a < 4; ++a)
            #pragma unroll
            for (int b = 0; b < 8; ++b) acc[a][b] = (f32x4){0.f, 0.f, 0.f, 0.f};

        const unsigned short* WIH = ws + WS_WIH;
        const unsigned short* WHH = ws + WS_WHH;

        #pragma unroll
        for (int ks = 0; ks < 8; ++ks) {
            const int xbase = (ks < 4) ? LDS_X : LDS_H;
            const int kb = (ks & 3) * 64 + lg * 16;
            bf16x8 af[4];
            #pragma unroll
            for (int mt = 0; mt < 4; ++mt) {
                int row = mt * 16 + ln;
                af[mt] = *reinterpret_cast<const bf16x8*>(sm + xbase + row * 256 + (kb ^ ((row & 7) << 4)));
            }
            const int kk = (ks & 3) * 32 + lg * 8;

            #define MFMA_JOB(job, Wptr, ob) { \
                bf16x8 bfr = *reinterpret_cast<const bf16x8*>((Wptr) + (size_t)((ob) + ln) * 128 + kk); \
                acc[0][job] = __builtin_amdgcn_mfma_f32_16x16x32_bf16(af[0], bfr, acc[0][job], 0, 0, 0); \
                acc[1][job] = __builtin_amdgcn_mfma_f32_16x16x32_bf16(af[1], bfr, acc[1][job], 0, 0, 0); \
                acc[2][job] = __builtin_amdgcn_mfma_f32_16x16x32_bf16(af[2], bfr, acc[2][job], 0, 0, 0); \
                acc[3][job] = __builtin_amdgcn_mfma_f32_16x16x32_bf16(af[3], bfr, acc[3][job], 0, 0, 0); }

            if (ks < 4) {
                MFMA_JOB(0, WIH, 32 * w);
                MFMA_JOB(1, WIH, 32 * w + 16);
                MFMA_JOB(2, WIH, 128 + 32 * w);
                MFMA_JOB(3, WIH, 144 + 32 * w);
                MFMA_JOB(4, WIH, 256 + 32 * w);
                MFMA_JOB(5, WIH, 272 + 32 * w);
            } else {
                MFMA_JOB(0, WHH, 32 * w);
                MFMA_JOB(1, WHH, 32 * w + 16);
                MFMA_JOB(2, WHH, 128 + 32 * w);
                MFMA_JOB(3, WHH, 144 + 32 * w);
                MFMA_JOB(6, WHH, 256 + 32 * w);
                MFMA_JOB(7, WHH, 272 + 32 * w);
            }
            #undef MFMA_JOB
        }

        // GRU epilogue (register-local per wave)
        #pragma unroll
        for (int jt = 0; jt < 2; ++jt) {
            int j = 32 * w + 16 * jt + ln;
            float br  = b_ih[j] + b_hh[j];
            float bz  = b_ih[128 + j] + b_hh[128 + j];
            float bxn = b_ih[256 + j];
            float bhn = b_hh[256 + j];
            #pragma unroll
            for (int mt = 0; mt < 4; ++mt) {
                #pragma unroll
                for (int i = 0; i < 4; ++i) {
                    int row = mt * 16 + lg * 4 + i;
                    int grow = row0 + row;
                    int lrow = (grow < N) ? grow : (N - 1);
                    float r  = sigmf(acc[mt][jt][i] + br);
                    float z  = sigmf(acc[mt][2 + jt][i] + bz);
                    float xn = acc[mt][4 + jt][i] + bxn;
                    float hn = acc[mt][6 + jt][i] + bhn;
                    float nn = tanh_fast(xn + r * hn);
                    float hp = h[(size_t)lrow * 128 + j];
                    float hv = (1.0f - z) * nn + z * hp;
                    if (grow < N) hnew[(size_t)grow * 128 + j] = hv;
                    int boff = LDS_HO + row * 256 + ((j * 2) ^ ((row & 7) << 4));
                    *reinterpret_cast<unsigned short*>(sm + boff) = f2bf(hv);
                }
            }
        }
    }
    __syncthreads();

    // ---------------- Phase 3: out = h_new @ dec_W.T + dec_b ----------------
    // wave w handles m-tile w (16 rows); dec_W padded to 16x128 (rows 5..15 zero)
    {
        f32x4 acc = (f32x4){0.f, 0.f, 0.f, 0.f};
        const unsigned short* DEC = ws + WS_DEC;
        #pragma unroll
        for (int ks = 0; ks < 4; ++ks) {
            int row = w * 16 + ln;
            bf16x8 af = *reinterpret_cast<const bf16x8*>(
                sm + LDS_HO + row * 256 + ((ks * 64 + lg * 16) ^ ((row & 7) << 4)));
            bf16x8 bf = *reinterpret_cast<const bf16x8*>(DEC + (size_t)ln * 128 + ks * 32 + lg * 8);
            acc = __builtin_amdgcn_mfma_f32_16x16x32_bf16(af, bf, acc, 0, 0, 0);
        }
        if (ln < 5) {
            float bias = dec_b[ln];
            #pragma unroll
            for (int i = 0; i < 4; ++i) {
                int grow = row0 + w * 16 + lg * 4 + i;
                if (grow < N) out[(size_t)grow * 5 + ln] = acc[i] + bias;
            }
        }
    }
}

extern "C" void kernel_launch(void* const* d_in, const int* in_sizes, int n_in,
                              void* d_out, int out_size, void* d_ws, size_t ws_size,
                              hipStream_t stream) {
    const float* pos     = (const float*)d_in[0];
    const float* h_other = (const float*)d_in[1];
    const float* h       = (const float*)d_in[2];
    const float* enc_W   = (const float*)d_in[3];
    const float* enc_b   = (const float*)d_in[4];
    const float* henc_W  = (const float*)d_in[5];
    const float* henc_b  = (const float*)d_in[6];
    const float* W_ih    = (const float*)d_in[7];
    const float* b_ih    = (const float*)d_in[8];
    const float* W_hh    = (const float*)d_in[9];
    const float* b_hh    = (const float*)d_in[10];
    const float* dec_W   = (const float*)d_in[11];
    const float* dec_b   = (const float*)d_in[12];

    int N = in_sizes[0] / 2;
    unsigned short* ws = (unsigned short*)d_ws;
    float* out  = (float*)d_out;
    float* hnew = out + (size_t)N * 5;

    hipLaunchKernelGGL(convert_weights_kernel, dim3((WS_TOTAL + 255) / 256), dim3(256), 0, stream,
                       W_ih, W_hh, henc_W, dec_W, ws);
    int blocks = (N + 63) / 64;
    hipLaunchKernelGGL(fused_rnn_kernel, dim3(blocks), dim3(256), 0, stream,
                       pos, h_other, h, enc_W, enc_b, henc_b, b_ih, b_hh, dec_b,
                       ws, out, hnew, N);
}